// Round 12
// baseline (220.947 us; speedup 1.0000x reference)
//
#include <hip/hip_runtime.h>
#include <math.h>

// Problem constants
#define B_N 2
#define S_N 2048
#define DM  512
#define H_N 8
#define DH  64
#define NC  32     // number of chunks = S/64
#define CH  64     // chunk length

typedef __bf16 bf16x8 __attribute__((ext_vector_type(8)));
typedef float  f32x4  __attribute__((ext_vector_type(4)));

__device__ __forceinline__ unsigned short f2bf(float f) {
    unsigned int u = __float_as_uint(f);
    u += 0x7FFFu + ((u >> 16) & 1u);          // round-to-nearest-even
    return (unsigned short)(u >> 16);
}

__device__ __forceinline__ void gload16(const void* g, void* l) {
    __builtin_amdgcn_global_load_lds(
        (const __attribute__((address_space(1))) unsigned int*)g,
        (__attribute__((address_space(3))) unsigned int*)l, 16, 0, 0);
}

// ---------------------------------------------------------------------------
// Kernel 0: fp32 -> bf16 conversion of x, Wqk, Wv, Wo.  Also zeroes the 16
// per-bh arrival counters used by gemm_qkv_fused's last-block scan.
// ---------------------------------------------------------------------------
__global__ __launch_bounds__(256) void convert_bf16(
    const float* __restrict__ x,  const float* __restrict__ wqk,
    const float* __restrict__ wv, const float* __restrict__ wo,
    unsigned short* __restrict__ xb,  unsigned short* __restrict__ wqkb,
    unsigned short* __restrict__ wvb, unsigned short* __restrict__ wob,
    unsigned* __restrict__ cnt)
{
    int gid = blockIdx.x * 256 + threadIdx.x;   // 0..786431 float4 units
    if (blockIdx.x == 0 && threadIdx.x < 16)
        __hip_atomic_store(&cnt[threadIdx.x], 0u, __ATOMIC_RELAXED, __HIP_MEMORY_SCOPE_AGENT);
    const float* src; unsigned short* dst; int off;
    if (gid < 524288)      { src = x;   dst = xb;   off = gid; }
    else if (gid < 655360) { src = wqk; dst = wqkb; off = gid - 524288; }
    else if (gid < 720896) { src = wv;  dst = wvb;  off = gid - 655360; }
    else                   { src = wo;  dst = wob;  off = gid - 720896; }
    float4 v = ((const float4*)src)[off];
    ushort4 r; r.x = f2bf(v.x); r.y = f2bf(v.y); r.z = f2bf(v.z); r.w = f2bf(v.w);
    ((ushort4*)dst)[off] = r;
}

// ---------------------------------------------------------------------------
// Kernel 1: fused projection + per-chunk state sums + LAST-BLOCK PREFIX SCAN.
// 64-row m-tiles, BK=64, global_load_lds staging (proven R8 structure).
// grid = (12, 64):  bx<4 -> q-blocks;  bx>=4 -> kv-blocks (head h=bx-4).
// After a kv-block writes its chunk's Asum/zsum it arrives at cnt[bh]; the
// 32nd arriver performs bh's exclusive chunk-prefix scan (states -> Sptb
// bf16, zsum in place).  No spinning, 16 low-contention counters.
// ---------------------------------------------------------------------------
__global__ __launch_bounds__(256) void gemm_qkv_fused(
    const unsigned short* __restrict__ xb,
    const unsigned short* __restrict__ Wqkb,
    const unsigned short* __restrict__ Wvb,
    const float* __restrict__ bqk, const float* __restrict__ bv,
    unsigned short* __restrict__ qb, unsigned short* __restrict__ kb_,
    unsigned short* __restrict__ vtb,
    float* __restrict__ Asum, float* __restrict__ zsum,
    unsigned short* __restrict__ Sptb, unsigned* __restrict__ cnt)
{
    __shared__ unsigned short Alds[2 * 64 * 32];    // [half][64][32]
    __shared__ unsigned short Blds[2 * 128 * 32];   // [half][128][32]
    __shared__ unsigned short ktT[64 * 72];
    __shared__ unsigned short vtT[64 * 72];
    __shared__ int lastflag;

    const int tid = threadIdx.x;
    const int w = tid >> 6, l = tid & 63;
    const int wm = w >> 1, wn = w & 1;
    const int lane15 = l & 15, quad = l >> 4;
    const int bx = blockIdx.x;
    const int m0 = blockIdx.y * 64;    // grid.y = 64
    const int isq = (bx < 4);
    const int h = isq ? 0 : (bx - 4);

    const int srow = w * 16 + (l >> 2);   // 0..63
    const int skof = (l & 3) << 3;

    f32x4 acc[2][4];
    #pragma unroll
    for (int i = 0; i < 2; i++)
        #pragma unroll
        for (int j = 0; j < 4; j++) acc[i][j] = (f32x4){0.f, 0.f, 0.f, 0.f};

    for (int k0 = 0; k0 < DM; k0 += 64) {
        __syncthreads();
        gload16(&xb[(size_t)(m0 + srow) * DM + k0 + skof],      (char*)Alds + w * 1024);
        gload16(&xb[(size_t)(m0 + srow) * DM + k0 + 32 + skof], (char*)Alds + 4096 + w * 1024);
        if (isq) {
            gload16(&Wqkb[(size_t)(bx * 128 + srow) * DM + k0 + skof],           (char*)Blds + w * 1024);
            gload16(&Wqkb[(size_t)(bx * 128 + 64 + srow) * DM + k0 + skof],      (char*)Blds + 4096 + w * 1024);
            gload16(&Wqkb[(size_t)(bx * 128 + srow) * DM + k0 + 32 + skof],      (char*)Blds + 8192 + w * 1024);
            gload16(&Wqkb[(size_t)(bx * 128 + 64 + srow) * DM + k0 + 32 + skof], (char*)Blds + 12288 + w * 1024);
        } else {
            gload16(&Wqkb[(size_t)(512 + h * 64 + srow) * DM + k0 + skof],       (char*)Blds + w * 1024);
            gload16(&Wvb[(size_t)(h * 64 + srow) * DM + k0 + skof],              (char*)Blds + 4096 + w * 1024);
            gload16(&Wqkb[(size_t)(512 + h * 64 + srow) * DM + k0 + 32 + skof],  (char*)Blds + 8192 + w * 1024);
            gload16(&Wvb[(size_t)(h * 64 + srow) * DM + k0 + 32 + skof],         (char*)Blds + 12288 + w * 1024);
        }
        __syncthreads();

        #pragma unroll
        for (int s = 0; s < 2; s++) {
            bf16x8 af[2], bfr[4];
            #pragma unroll
            for (int i = 0; i < 2; i++)
                af[i] = *(bf16x8*)&Alds[s * 2048 + (wm * 32 + i * 16 + lane15) * 32 + quad * 8];
            #pragma unroll
            for (int j = 0; j < 4; j++)
                bfr[j] = *(bf16x8*)&Blds[s * 4096 + (wn * 64 + j * 16 + lane15) * 32 + quad * 8];
            #pragma unroll
            for (int i = 0; i < 2; i++)
                #pragma unroll
                for (int j = 0; j < 4; j++)
                    acc[i][j] = __builtin_amdgcn_mfma_f32_16x16x32_bf16(af[i], bfr[j], acc[i][j], 0, 0, 0);
        }
    }

    const int bbu = m0 >> 11;          // batch index (block-uniform)
    const int t0  = m0 & (S_N - 1);    // global t of local row 0
    const int c0  = t0 >> 6;           // chunk index

    if (isq) {
        #pragma unroll
        for (int i = 0; i < 2; i++) {
            #pragma unroll
            for (int rg = 0; rg < 4; rg++) {
                int m = m0 + wm * 32 + i * 16 + quad * 4 + rg;
                int bb = m >> 11, t = m & (S_N - 1);
                #pragma unroll
                for (int j = 0; j < 4; j++) {
                    int n = bx * 128 + wn * 64 + j * 16 + lane15;   // 0..511
                    float val = acc[i][j][rg] + bqk[n];
                    val = (val > 0.f) ? (val + 1.f) : __expf(val);
                    qb[(((size_t)bb * H_N + (n >> 6)) * S_N + t) * DH + (n & 63)] = f2bf(val);
                }
            }
        }
        return;
    }

    // ---- kv epilogue: wn==0 half is k (elu+1), wn==1 half is v ----
    #pragma unroll
    for (int i = 0; i < 2; i++) {
        #pragma unroll
        for (int rg = 0; rg < 4; rg++) {
            int tl = wm * 32 + i * 16 + quad * 4 + rg;   // local row 0..63
            int t  = t0 + tl;
            #pragma unroll
            for (int j = 0; j < 4; j++) {
                int col = j * 16 + lane15;               // 0..63 within half
                if (wn == 0) {
                    float val = acc[i][j][rg] + bqk[512 + h * 64 + col];
                    val = (val > 0.f) ? (val + 1.f) : __expf(val);
                    unsigned short us = f2bf(val);
                    kb_[(((size_t)bbu * H_N + h) * S_N + t) * DH + col] = us;
                    ktT[col * 72 + tl] = us;
                } else {
                    float val = acc[i][j][rg] + bv[h * 64 + col];
                    vtT[col * 72 + tl] = f2bf(val);
                }
            }
        }
    }
    __syncthreads();

    // ---- coalesced copy vT -> vtb global [bh][d][t] ----
    {
        size_t vbase = (((size_t)bbu * H_N + h) * DH) * S_N + t0;
        #pragma unroll
        for (int it = 0; it < 2; it++) {
            int idx = it * 2048 + tid * 8;
            int d = idx >> 6, tt = idx & 63;
            *(bf16x8*)&vtb[vbase + (size_t)d * S_N + tt] = *(bf16x8*)&vtT[d * 72 + tt];
        }
    }

    // ---- St via MFMA; wave w owns d2 rows 16w..16w+15 ----
    {
        int blk = ((bbu * H_N + h) * NC) + c0;
        bf16x8 va[2];
        #pragma unroll
        for (int s = 0; s < 2; s++)
            va[s] = *(bf16x8*)&vtT[(w * 16 + lane15) * 72 + s * 32 + quad * 8];
        f32x4 sacc[4];
        #pragma unroll
        for (int j = 0; j < 4; j++) sacc[j] = (f32x4){0.f, 0.f, 0.f, 0.f};
        #pragma unroll
        for (int j = 0; j < 4; j++)
            #pragma unroll
            for (int s = 0; s < 2; s++) {
                bf16x8 kB = *(bf16x8*)&ktT[(j * 16 + lane15) * 72 + s * 32 + quad * 8];
                sacc[j] = __builtin_amdgcn_mfma_f32_16x16x32_bf16(va[s], kB, sacc[j], 0, 0, 0);
            }
        #pragma unroll
        for (int j = 0; j < 4; j++)
            #pragma unroll
            for (int rg = 0; rg < 4; rg++)
                Asum[(size_t)blk * 4096 + (w * 16 + quad * 4 + rg) * 64 + j * 16 + lane15] = sacc[j][rg];
    }

    // ---- z: threads 0..63, one d1 each ----
    if (tid < 64) {
        float z = 0.f;
        #pragma unroll
        for (int p = 0; p < 8; p++) {
            bf16x8 kk = *(bf16x8*)&ktT[tid * 72 + p * 8];
            #pragma unroll
            for (int e = 0; e < 8; e++) z += (float)kk[e];
        }
        zsum[(size_t)((bbu * H_N + h) * NC + c0) * 64 + tid] = z;
    }

    // ---- arrive; 32nd arriver for this bh performs the prefix scan ----
    __threadfence();                  // release this block's Asum/zsum writes
    __syncthreads();
    if (tid == 0) {
        unsigned old = __hip_atomic_fetch_add(&cnt[bbu * H_N + h], 1u,
                          __ATOMIC_ACQ_REL, __HIP_MEMORY_SCOPE_AGENT);
        lastflag = (old == NC - 1);
    }
    __syncthreads();
    if (!lastflag) return;
    __threadfence();                  // acquire: see all peers' writes

    {
        const int bh = bbu * H_N + h;
        const float* abase = Asum + (size_t)bh * NC * 4096;
        unsigned short* sbase = Sptb + (size_t)bh * NC * 4096;
        const int e = tid * 16;       // 16 state elements per thread
        float4 a0 = {0,0,0,0}, a1 = {0,0,0,0}, a2 = {0,0,0,0}, a3 = {0,0,0,0};
        #pragma unroll 4
        for (int cc = 0; cc < NC; cc++) {
            const float4* p = (const float4*)(abase + (size_t)cc * 4096 + e);
            float4 p0 = p[0], p1 = p[1], p2 = p[2], p3 = p[3];
            ushort4 u0 = {f2bf(a0.x), f2bf(a0.y), f2bf(a0.z), f2bf(a0.w)};
            ushort4 u1 = {f2bf(a1.x), f2bf(a1.y), f2bf(a1.z), f2bf(a1.w)};
            ushort4 u2 = {f2bf(a2.x), f2bf(a2.y), f2bf(a2.z), f2bf(a2.w)};
            ushort4 u3 = {f2bf(a3.x), f2bf(a3.y), f2bf(a3.z), f2bf(a3.w)};
            unsigned short* sp = sbase + (size_t)cc * 4096 + e;
            *(ushort4*)(sp)      = u0;
            *(ushort4*)(sp + 4)  = u1;
            *(ushort4*)(sp + 8)  = u2;
            *(ushort4*)(sp + 12) = u3;
            a0.x += p0.x; a0.y += p0.y; a0.z += p0.z; a0.w += p0.w;
            a1.x += p1.x; a1.y += p1.y; a1.z += p1.z; a1.w += p1.w;
            a2.x += p2.x; a2.y += p2.y; a2.z += p2.z; a2.w += p2.w;
            a3.x += p3.x; a3.y += p3.y; a3.z += p3.z; a3.w += p3.w;
        }
        if (tid < 64) {
            size_t zb = (size_t)bh * NC * 64 + tid;
            float vals[NC];
            #pragma unroll
            for (int cc = 0; cc < NC; cc++) vals[cc] = zsum[zb + cc * 64];
            float zacc = 0.f;
            #pragma unroll
            for (int cc = 0; cc < NC; cc++) {
                float tmp = vals[cc];
                zsum[zb + cc * 64] = zacc;
                zacc += tmp;
            }
        }
    }
}

// ---------------------------------------------------------------------------
// Kernel 2: per-chunk attention, all-MFMA (R8-proven version).
// ---------------------------------------------------------------------------
__global__ __launch_bounds__(256) void attn_mfma(
    const unsigned short* __restrict__ qb, const unsigned short* __restrict__ kb_,
    const unsigned short* __restrict__ vtb, const unsigned short* __restrict__ Sptb,
    const float* __restrict__ zsum, unsigned short* __restrict__ ctxb)
{
    __shared__ __align__(16) unsigned short P[64 * 72];
    __shared__ float nupart[64][4];

    const int blk = blockIdx.x;           // 0..511
    const int bh = blk >> 5, c = blk & 31;
    const int b = bh >> 3, h = bh & 7;
    const int tid = threadIdx.x;
    const int w = tid >> 6, l = tid & 63;
    const int lane15 = l & 15, quad = l >> 4;

    const unsigned short* qc  = qb  + (size_t)bh * S_N * DH + c * CH * DH;  // [t][d]
    const unsigned short* kc  = kb_ + (size_t)bh * S_N * DH + c * CH * DH;  // [u][d]
    const unsigned short* vtc = vtb + (size_t)bh * DH * S_N + c * CH;       // [d2][t], stride S_N
    const unsigned short* spc = Sptb + (size_t)blk * 4096;                  // [d2][d1]
    const float* zc = zsum + (size_t)blk * 64;

    bf16x8 af[2];
    #pragma unroll
    for (int s = 0; s < 2; s++)
        af[s] = *(const bf16x8*)&qc[(w * 16 + lane15) * DH + s * 32 + quad * 8];

    // scores S[t][u]
    f32x4 sacc[4];
    #pragma unroll
    for (int j = 0; j < 4; j++) sacc[j] = (f32x4){0.f, 0.f, 0.f, 0.f};
    #pragma unroll
    for (int j = 0; j < 4; j++)
        #pragma unroll
        for (int s = 0; s < 2; s++) {
            bf16x8 bk = *(const bf16x8*)&kc[(j * 16 + lane15) * DH + s * 32 + quad * 8];
            sacc[j] = __builtin_amdgcn_mfma_f32_16x16x32_bf16(af[s], bk, sacc[j], 0, 0, 0);
        }

    // causal mask + store P (bf16) to LDS
    const int r0 = w * 16 + quad * 4;
    #pragma unroll
    for (int j = 0; j < 4; j++) {
        int u = j * 16 + lane15;
        #pragma unroll
        for (int rg = 0; rg < 4; rg++) {
            int rr = r0 + rg;
            float v = (u <= rr) ? sacc[j][rg] : 0.f;
            P[rr * 72 + u] = f2bf(v);
        }
    }
    __syncthreads();

    // nu: thread (tl, part) sums P[tl][16*part..+15] + q.zprev strip
    const int tl = tid >> 2, part = tid & 3;
    float nup = 0.f;
    {
        bf16x8 p0 = *(const bf16x8*)&P[tl * 72 + part * 16];
        bf16x8 p1 = *(const bf16x8*)&P[tl * 72 + part * 16 + 8];
        bf16x8 q0 = *(const bf16x8*)&qc[tl * DH + part * 16];
        bf16x8 q1 = *(const bf16x8*)&qc[tl * DH + part * 16 + 8];
        #pragma unroll
        for (int i = 0; i < 8; i++) {
            nup += (float)p0[i] + (float)p1[i];
            nup += (float)q0[i] * zc[part * 16 + i];
            nup += (float)q1[i] * zc[part * 16 + 8 + i];
        }
    }
    nupart[tl][part] = nup;
    __syncthreads();

    // numerator: intra (P @ vt) + inter (q @ Spt), fused accumulator
    bf16x8 pa[2];
    #pragma unroll
    for (int s = 0; s < 2; s++)
        pa[s] = *(const bf16x8*)&P[(w * 16 + lane15) * 72 + s * 32 + quad * 8];

    f32x4 acc[4];
    #pragma unroll
    for (int j = 0; j < 4; j++) acc[j] = (f32x4){0.f, 0.f, 0.f, 0.f};
    #pragma unroll
    for (int j = 0; j < 4; j++)
        #pragma unroll
        for (int s = 0; s < 2; s++) {
            bf16x8 bv8 = *(const bf16x8*)&vtc[(size_t)(j * 16 + lane15) * S_N + s * 32 + quad * 8];
            acc[j] = __builtin_amdgcn_mfma_f32_16x16x32_bf16(pa[s], bv8, acc[j], 0, 0, 0);
            bf16x8 bs = *(const bf16x8*)&spc[(j * 16 + lane15) * 64 + s * 32 + quad * 8];
            acc[j] = __builtin_amdgcn_mfma_f32_16x16x32_bf16(af[s], bs, acc[j], 0, 0, 0);
        }

    // epilogue: divide by nu, write ctx bf16 [b*S+t][DM]
    #pragma unroll
    for (int rg = 0; rg < 4; rg++) {
        int rr = r0 + rg;
        float nu = nupart[rr][0] + nupart[rr][1] + nupart[rr][2] + nupart[rr][3];
        float inv = 1.f / nu;
        size_t obase = ((size_t)b * S_N + c * CH + rr) * DM + h * DH;
        #pragma unroll
        for (int j = 0; j < 4; j++)
            ctxb[obase + j * 16 + lane15] = f2bf(acc[j][rg] * inv);
    }
}

// ---------------------------------------------------------------------------
// Kernel 3: output projection via bf16 MFMA.  64x64 tiles, BK=64, grid (8,64).
// ---------------------------------------------------------------------------
__global__ __launch_bounds__(256) void gemm_out_mfma(
    const unsigned short* __restrict__ ctxb,
    const unsigned short* __restrict__ Wob,
    const float* __restrict__ bo, float* __restrict__ out)
{
    __shared__ unsigned short Alds[2 * 64 * 32];
    __shared__ unsigned short Blds[2 * 64 * 32];
    const int tid = threadIdx.x;
    const int w = tid >> 6, l = tid & 63;
    const int wm = w >> 1, wn = w & 1;
    const int lane15 = l & 15, quad = l >> 4;
    const int n0 = blockIdx.x * 64;    // grid.x = 8
    const int m0 = blockIdx.y * 64;    // grid.y = 64

    const int srow = w * 16 + (l >> 2);
    const int skof = (l & 3) << 3;

    f32x4 acc[2][2];
    #pragma unroll
    for (int i = 0; i < 2; i++)
        #pragma unroll
        for (int j = 0; j < 2; j++) acc[i][j] = (f32x4){0.f, 0.f, 0.f, 0.f};

    for (int k0 = 0; k0 < DM; k0 += 64) {
        __syncthreads();
        gload16(&ctxb[(size_t)(m0 + srow) * DM + k0 + skof],      (char*)Alds + w * 1024);
        gload16(&ctxb[(size_t)(m0 + srow) * DM + k0 + 32 + skof], (char*)Alds + 4096 + w * 1024);
        gload16(&Wob[(size_t)(n0 + srow) * DM + k0 + skof],       (char*)Blds + w * 1024);
        gload16(&Wob[(size_t)(n0 + srow) * DM + k0 + 32 + skof],  (char*)Blds + 4096 + w * 1024);
        __syncthreads();

        #pragma unroll
        for (int s = 0; s < 2; s++) {
            bf16x8 af2[2], bfr[2];
            #pragma unroll
            for (int i = 0; i < 2; i++)
                af2[i] = *(bf16x8*)&Alds[s * 2048 + (wm * 32 + i * 16 + lane15) * 32 + quad * 8];
            #pragma unroll
            for (int j = 0; j < 2; j++)
                bfr[j] = *(bf16x8*)&Blds[s * 2048 + (wn * 32 + j * 16 + lane15) * 32 + quad * 8];
            #pragma unroll
            for (int i = 0; i < 2; i++)
                #pragma unroll
                for (int j = 0; j < 2; j++)
                    acc[i][j] = __builtin_amdgcn_mfma_f32_16x16x32_bf16(af2[i], bfr[j], acc[i][j], 0, 0, 0);
        }
    }

    #pragma unroll
    for (int i = 0; i < 2; i++) {
        #pragma unroll
        for (int rg = 0; rg < 4; rg++) {
            int m = m0 + wm * 32 + i * 16 + quad * 4 + rg;
            #pragma unroll
            for (int j = 0; j < 2; j++) {
                int n = n0 + wn * 32 + j * 16 + lane15;
                out[(size_t)m * DM + n] = acc[i][j][rg] + bo[n];
            }
        }
    }
}

// ---------------------------------------------------------------------------
extern "C" void kernel_launch(void* const* d_in, const int* in_sizes, int n_in,
                              void* d_out, int out_size, void* d_ws, size_t ws_size,
                              hipStream_t stream)
{
    const float* x   = (const float*)d_in[0];
    const float* Wqk = (const float*)d_in[1];
    const float* bqk = (const float*)d_in[2];
    const float* Wv  = (const float*)d_in[3];
    const float* bv  = (const float*)d_in[4];
    const float* Wo  = (const float*)d_in[5];
    const float* bo  = (const float*)d_in[6];
    float* out = (float*)d_out;

    const size_t NTOK = (size_t)B_N * S_N * DM;   // 2,097,152
    float* Asum = (float*)d_ws;                   // NTOK fp32
    float* zsum = Asum + NTOK;                    // 32768 fp32
    unsigned short* xb   = (unsigned short*)(zsum + 32768);
    unsigned short* Wqkb = xb   + NTOK;
    unsigned short* Wvb  = Wqkb + 524288;
    unsigned short* Wob  = Wvb  + 262144;
    unsigned short* qb   = Wob  + 262144;
    unsigned short* kb_  = qb   + NTOK;
    unsigned short* vtb  = kb_  + NTOK;
    unsigned short* Sptb = vtb  + NTOK;
    unsigned short* ctxb = Sptb + NTOK;
    unsigned* cnt        = (unsigned*)(ctxb + NTOK);   // 16 arrival counters

    convert_bf16  <<<dim3(3072),   256, 0, stream>>>(x, Wqk, Wv, Wo, xb, Wqkb, Wvb, Wob, cnt);
    gemm_qkv_fused<<<dim3(12, 64), 256, 0, stream>>>(xb, Wqkb, Wvb, bqk, bv, qb, kb_, vtb,
                                                     Asum, zsum, Sptb, cnt);
    attn_mfma     <<<dim3(512),    256, 0, stream>>>(qb, kb_, vtb, Sptb, zsum, ctxb);
    gemm_out_mfma <<<dim3(8, 64),  256, 0, stream>>>(ctxb, Wob, bo, out);
}

// Round 13
// 112.907 us; speedup vs baseline: 1.9569x; 1.9569x over previous
//
#include <hip/hip_runtime.h>
#include <math.h>

// Problem constants
#define B_N 2
#define S_N 2048
#define DM  512
#define H_N 8
#define DH  64
#define NC  32     // number of chunks = S/64
#define CH  64     // chunk length

typedef __bf16 bf16x8 __attribute__((ext_vector_type(8)));
typedef float  f32x4  __attribute__((ext_vector_type(4)));

__device__ __forceinline__ unsigned short f2bf(float f) {
    unsigned int u = __float_as_uint(f);
    u += 0x7FFFu + ((u >> 16) & 1u);          // round-to-nearest-even
    return (unsigned short)(u >> 16);
}

__device__ __forceinline__ void gload16(const void* g, void* l) {
    __builtin_amdgcn_global_load_lds(
        (const __attribute__((address_space(1))) unsigned int*)g,
        (__attribute__((address_space(3))) unsigned int*)l, 16, 0, 0);
}

// ---------------------------------------------------------------------------
// Kernel 0: fp32 -> bf16 conversion of x, Wqk, Wv, Wo.
// ---------------------------------------------------------------------------
__global__ __launch_bounds__(256) void convert_bf16(
    const float* __restrict__ x,  const float* __restrict__ wqk,
    const float* __restrict__ wv, const float* __restrict__ wo,
    unsigned short* __restrict__ xb,  unsigned short* __restrict__ wqkb,
    unsigned short* __restrict__ wvb, unsigned short* __restrict__ wob)
{
    int gid = blockIdx.x * 256 + threadIdx.x;   // 0..786431 float4 units
    const float* src; unsigned short* dst; int off;
    if (gid < 524288)      { src = x;   dst = xb;   off = gid; }
    else if (gid < 655360) { src = wqk; dst = wqkb; off = gid - 524288; }
    else if (gid < 720896) { src = wv;  dst = wvb;  off = gid - 655360; }
    else                   { src = wo;  dst = wob;  off = gid - 720896; }
    float4 v = ((const float4*)src)[off];
    ushort4 r; r.x = f2bf(v.x); r.y = f2bf(v.y); r.z = f2bf(v.z); r.w = f2bf(v.w);
    ((ushort4*)dst)[off] = r;
}

// ---------------------------------------------------------------------------
// Kernel 1: fused projection + per-chunk state sums.  64-row m-tiles, BK=64.
// grid = (12, 64):  bx<4  -> q-blocks;  bx>=4 -> kv-blocks (head h=bx-4).
// BK=64 staged as two [64][32] (A) / [128][32] (B) sub-tiles via
// global_load_lds (R8-proven; direct global fragment loads measured 3x worse).
// ---------------------------------------------------------------------------
__global__ __launch_bounds__(256) void gemm_qkv_fused(
    const unsigned short* __restrict__ xb,
    const unsigned short* __restrict__ Wqkb,
    const unsigned short* __restrict__ Wvb,
    const float* __restrict__ bqk, const float* __restrict__ bv,
    unsigned short* __restrict__ qb, unsigned short* __restrict__ kb_,
    unsigned short* __restrict__ vtb,
    float* __restrict__ Asum, float* __restrict__ zsum)
{
    __shared__ unsigned short Alds[2 * 64 * 32];    // [half][64][32]
    __shared__ unsigned short Blds[2 * 128 * 32];   // [half][128][32]
    __shared__ unsigned short ktT[64 * 72];
    __shared__ unsigned short vtT[64 * 72];

    const int tid = threadIdx.x;
    const int w = tid >> 6, l = tid & 63;
    const int wm = w >> 1, wn = w & 1;
    const int lane15 = l & 15, quad = l >> 4;
    const int bx = blockIdx.x;
    const int m0 = blockIdx.y * 64;    // grid.y = 64
    const int isq = (bx < 4);
    const int h = isq ? 0 : (bx - 4);

    const int srow = w * 16 + (l >> 2);   // 0..63
    const int skof = (l & 3) << 3;

    f32x4 acc[2][4];
    #pragma unroll
    for (int i = 0; i < 2; i++)
        #pragma unroll
        for (int j = 0; j < 4; j++) acc[i][j] = (f32x4){0.f, 0.f, 0.f, 0.f};

    for (int k0 = 0; k0 < DM; k0 += 64) {
        __syncthreads();
        gload16(&xb[(size_t)(m0 + srow) * DM + k0 + skof],      (char*)Alds + w * 1024);
        gload16(&xb[(size_t)(m0 + srow) * DM + k0 + 32 + skof], (char*)Alds + 4096 + w * 1024);
        if (isq) {
            gload16(&Wqkb[(size_t)(bx * 128 + srow) * DM + k0 + skof],           (char*)Blds + w * 1024);
            gload16(&Wqkb[(size_t)(bx * 128 + 64 + srow) * DM + k0 + skof],      (char*)Blds + 4096 + w * 1024);
            gload16(&Wqkb[(size_t)(bx * 128 + srow) * DM + k0 + 32 + skof],      (char*)Blds + 8192 + w * 1024);
            gload16(&Wqkb[(size_t)(bx * 128 + 64 + srow) * DM + k0 + 32 + skof], (char*)Blds + 12288 + w * 1024);
        } else {
            gload16(&Wqkb[(size_t)(512 + h * 64 + srow) * DM + k0 + skof],       (char*)Blds + w * 1024);
            gload16(&Wvb[(size_t)(h * 64 + srow) * DM + k0 + skof],              (char*)Blds + 4096 + w * 1024);
            gload16(&Wqkb[(size_t)(512 + h * 64 + srow) * DM + k0 + 32 + skof],  (char*)Blds + 8192 + w * 1024);
            gload16(&Wvb[(size_t)(h * 64 + srow) * DM + k0 + 32 + skof],         (char*)Blds + 12288 + w * 1024);
        }
        __syncthreads();

        #pragma unroll
        for (int s = 0; s < 2; s++) {
            bf16x8 af[2], bfr[4];
            #pragma unroll
            for (int i = 0; i < 2; i++)
                af[i] = *(bf16x8*)&Alds[s * 2048 + (wm * 32 + i * 16 + lane15) * 32 + quad * 8];
            #pragma unroll
            for (int j = 0; j < 4; j++)
                bfr[j] = *(bf16x8*)&Blds[s * 4096 + (wn * 64 + j * 16 + lane15) * 32 + quad * 8];
            #pragma unroll
            for (int i = 0; i < 2; i++)
                #pragma unroll
                for (int j = 0; j < 4; j++)
                    acc[i][j] = __builtin_amdgcn_mfma_f32_16x16x32_bf16(af[i], bfr[j], acc[i][j], 0, 0, 0);
        }
    }

    const int bbu = m0 >> 11;          // batch index (block-uniform)
    const int t0  = m0 & (S_N - 1);    // global t of local row 0
    const int c0  = t0 >> 6;           // chunk index

    if (isq) {
        #pragma unroll
        for (int i = 0; i < 2; i++) {
            #pragma unroll
            for (int rg = 0; rg < 4; rg++) {
                int m = m0 + wm * 32 + i * 16 + quad * 4 + rg;
                int bb = m >> 11, t = m & (S_N - 1);
                #pragma unroll
                for (int j = 0; j < 4; j++) {
                    int n = bx * 128 + wn * 64 + j * 16 + lane15;   // 0..511
                    float val = acc[i][j][rg] + bqk[n];
                    val = (val > 0.f) ? (val + 1.f) : __expf(val);
                    qb[(((size_t)bb * H_N + (n >> 6)) * S_N + t) * DH + (n & 63)] = f2bf(val);
                }
            }
        }
        return;
    }

    // ---- kv epilogue: wn==0 half is k (elu+1), wn==1 half is v ----
    #pragma unroll
    for (int i = 0; i < 2; i++) {
        #pragma unroll
        for (int rg = 0; rg < 4; rg++) {
            int tl = wm * 32 + i * 16 + quad * 4 + rg;   // local row 0..63
            int t  = t0 + tl;
            #pragma unroll
            for (int j = 0; j < 4; j++) {
                int col = j * 16 + lane15;               // 0..63 within half
                if (wn == 0) {
                    float val = acc[i][j][rg] + bqk[512 + h * 64 + col];
                    val = (val > 0.f) ? (val + 1.f) : __expf(val);
                    unsigned short us = f2bf(val);
                    kb_[(((size_t)bbu * H_N + h) * S_N + t) * DH + col] = us;
                    ktT[col * 72 + tl] = us;
                } else {
                    float val = acc[i][j][rg] + bv[h * 64 + col];
                    vtT[col * 72 + tl] = f2bf(val);
                }
            }
        }
    }
    __syncthreads();

    // ---- coalesced copy vT -> vtb global [bh][d][t] ----
    {
        size_t vbase = (((size_t)bbu * H_N + h) * DH) * S_N + t0;
        #pragma unroll
        for (int it = 0; it < 2; it++) {
            int idx = it * 2048 + tid * 8;
            int d = idx >> 6, tt = idx & 63;
            *(bf16x8*)&vtb[vbase + (size_t)d * S_N + tt] = *(bf16x8*)&vtT[d * 72 + tt];
        }
    }

    // ---- St via MFMA; wave w owns d2 rows 16w..16w+15 ----
    {
        int blk = ((bbu * H_N + h) * NC) + c0;
        bf16x8 va[2];
        #pragma unroll
        for (int s = 0; s < 2; s++)
            va[s] = *(bf16x8*)&vtT[(w * 16 + lane15) * 72 + s * 32 + quad * 8];
        f32x4 sacc[4];
        #pragma unroll
        for (int j = 0; j < 4; j++) sacc[j] = (f32x4){0.f, 0.f, 0.f, 0.f};
        #pragma unroll
        for (int j = 0; j < 4; j++)
            #pragma unroll
            for (int s = 0; s < 2; s++) {
                bf16x8 kB = *(bf16x8*)&ktT[(j * 16 + lane15) * 72 + s * 32 + quad * 8];
                sacc[j] = __builtin_amdgcn_mfma_f32_16x16x32_bf16(va[s], kB, sacc[j], 0, 0, 0);
            }
        #pragma unroll
        for (int j = 0; j < 4; j++)
            #pragma unroll
            for (int rg = 0; rg < 4; rg++)
                Asum[(size_t)blk * 4096 + (w * 16 + quad * 4 + rg) * 64 + j * 16 + lane15] = sacc[j][rg];
    }

    // ---- z: threads 0..63, one d1 each ----
    if (tid < 64) {
        float z = 0.f;
        #pragma unroll
        for (int p = 0; p < 8; p++) {
            bf16x8 kk = *(bf16x8*)&ktT[tid * 72 + p * 8];
            #pragma unroll
            for (int e = 0; e < 8; e++) z += (float)kk[e];
        }
        zsum[(size_t)((bbu * H_N + h) * NC + c0) * 64 + tid] = z;
    }
}

// ---------------------------------------------------------------------------
// Kernel 2: exclusive prefix scan over chunks — register-batched.
// ---------------------------------------------------------------------------
__global__ __launch_bounds__(256) void scan_states(
    const float* __restrict__ Asum, float* __restrict__ zsum,
    unsigned short* __restrict__ Sptb)
{
    const int gid = blockIdx.x * 256 + threadIdx.x;   // 0..66559
    const int bh = gid / 4160;
    const int r  = gid % 4160;
    if (r < 4096) {
        size_t base = (size_t)bh * NC * 4096 + r;
        float vals[NC];
        #pragma unroll
        for (int c = 0; c < NC; c++) vals[c] = Asum[base + (size_t)c * 4096];
        float acc = 0.f;
        #pragma unroll
        for (int c = 0; c < NC; c++) {
            float tmp = vals[c];
            Sptb[base + (size_t)c * 4096] = f2bf(acc);
            acc += tmp;
        }
    } else {
        int d = r - 4096;
        size_t base = (size_t)bh * NC * 64 + d;
        float vals[NC];
        #pragma unroll
        for (int c = 0; c < NC; c++) vals[c] = zsum[base + (size_t)c * 64];
        float acc = 0.f;
        #pragma unroll
        for (int c = 0; c < NC; c++) {
            float tmp = vals[c];
            zsum[base + (size_t)c * 64] = acc;
            acc += tmp;
        }
    }
}

// ---------------------------------------------------------------------------
// Kernel 3: per-chunk attention, all-MFMA.  Spt fragments prefetched into
// registers before the P/nu phase (no dependence on P) so their global-load
// latency overlaps the score MFMAs + P stores.
// ---------------------------------------------------------------------------
__global__ __launch_bounds__(256) void attn_mfma(
    const unsigned short* __restrict__ qb, const unsigned short* __restrict__ kb_,
    const unsigned short* __restrict__ vtb, const unsigned short* __restrict__ Sptb,
    const float* __restrict__ zsum, unsigned short* __restrict__ ctxb)
{
    __shared__ __align__(16) unsigned short P[64 * 72];
    __shared__ float nupart[64][4];

    const int blk = blockIdx.x;           // 0..511
    const int bh = blk >> 5, c = blk & 31;
    const int b = bh >> 3, h = bh & 7;
    const int tid = threadIdx.x;
    const int w = tid >> 6, l = tid & 63;
    const int lane15 = l & 15, quad = l >> 4;

    const unsigned short* qc  = qb  + (size_t)bh * S_N * DH + c * CH * DH;  // [t][d]
    const unsigned short* kc  = kb_ + (size_t)bh * S_N * DH + c * CH * DH;  // [u][d]
    const unsigned short* vtc = vtb + (size_t)bh * DH * S_N + c * CH;       // [d2][t], stride S_N
    const unsigned short* spc = Sptb + (size_t)blk * 4096;                  // [d2][d1]
    const float* zc = zsum + (size_t)blk * 64;

    bf16x8 af[2];
    #pragma unroll
    for (int s = 0; s < 2; s++)
        af[s] = *(const bf16x8*)&qc[(w * 16 + lane15) * DH + s * 32 + quad * 8];

    // prefetch Spt fragments early — consumed after the P/nu phase
    bf16x8 bs[4][2];
    #pragma unroll
    for (int j = 0; j < 4; j++)
        #pragma unroll
        for (int s = 0; s < 2; s++)
            bs[j][s] = *(const bf16x8*)&spc[(j * 16 + lane15) * 64 + s * 32 + quad * 8];

    // scores S[t][u]
    f32x4 sacc[4];
    #pragma unroll
    for (int j = 0; j < 4; j++) sacc[j] = (f32x4){0.f, 0.f, 0.f, 0.f};
    #pragma unroll
    for (int j = 0; j < 4; j++)
        #pragma unroll
        for (int s = 0; s < 2; s++) {
            bf16x8 bk = *(const bf16x8*)&kc[(j * 16 + lane15) * DH + s * 32 + quad * 8];
            sacc[j] = __builtin_amdgcn_mfma_f32_16x16x32_bf16(af[s], bk, sacc[j], 0, 0, 0);
        }

    // causal mask + store P (bf16) to LDS
    const int r0 = w * 16 + quad * 4;
    #pragma unroll
    for (int j = 0; j < 4; j++) {
        int u = j * 16 + lane15;
        #pragma unroll
        for (int rg = 0; rg < 4; rg++) {
            int rr = r0 + rg;
            float v = (u <= rr) ? sacc[j][rg] : 0.f;
            P[rr * 72 + u] = f2bf(v);
        }
    }
    __syncthreads();

    // nu: thread (tl, part) sums P[tl][16*part..+15] + q.zprev strip
    const int tl = tid >> 2, part = tid & 3;
    float nup = 0.f;
    {
        bf16x8 p0 = *(const bf16x8*)&P[tl * 72 + part * 16];
        bf16x8 p1 = *(const bf16x8*)&P[tl * 72 + part * 16 + 8];
        bf16x8 q0 = *(const bf16x8*)&qc[tl * DH + part * 16];
        bf16x8 q1 = *(const bf16x8*)&qc[tl * DH + part * 16 + 8];
        #pragma unroll
        for (int i = 0; i < 8; i++) {
            nup += (float)p0[i] + (float)p1[i];
            nup += (float)q0[i] * zc[part * 16 + i];
            nup += (float)q1[i] * zc[part * 16 + 8 + i];
        }
    }
    nupart[tl][part] = nup;
    __syncthreads();

    // numerator: intra (P @ vt) + inter (q @ Spt), fused accumulator
    bf16x8 pa[2];
    #pragma unroll
    for (int s = 0; s < 2; s++)
        pa[s] = *(const bf16x8*)&P[(w * 16 + lane15) * 72 + s * 32 + quad * 8];

    f32x4 acc[4];
    #pragma unroll
    for (int j = 0; j < 4; j++) acc[j] = (f32x4){0.f, 0.f, 0.f, 0.f};
    #pragma unroll
    for (int j = 0; j < 4; j++)
        #pragma unroll
        for (int s = 0; s < 2; s++) {
            bf16x8 bv8 = *(const bf16x8*)&vtc[(size_t)(j * 16 + lane15) * S_N + s * 32 + quad * 8];
            acc[j] = __builtin_amdgcn_mfma_f32_16x16x32_bf16(pa[s], bv8, acc[j], 0, 0, 0);
            acc[j] = __builtin_amdgcn_mfma_f32_16x16x32_bf16(af[s], bs[j][s], acc[j], 0, 0, 0);
        }

    // epilogue: divide by nu, write ctx bf16 [b*S+t][DM]
    #pragma unroll
    for (int rg = 0; rg < 4; rg++) {
        int rr = r0 + rg;
        float nu = nupart[rr][0] + nupart[rr][1] + nupart[rr][2] + nupart[rr][3];
        float inv = 1.f / nu;
        size_t obase = ((size_t)b * S_N + c * CH + rr) * DM + h * DH;
        #pragma unroll
        for (int j = 0; j < 4; j++)
            ctxb[obase + j * 16 + lane15] = f2bf(acc[j][rg] * inv);
    }
}

// ---------------------------------------------------------------------------
// Kernel 4: output projection via bf16 MFMA.  64x64 tiles, BK=64, grid (8,64).
// ---------------------------------------------------------------------------
__global__ __launch_bounds__(256) void gemm_out_mfma(
    const unsigned short* __restrict__ ctxb,
    const unsigned short* __restrict__ Wob,
    const float* __restrict__ bo, float* __restrict__ out)
{
    __shared__ unsigned short Alds[2 * 64 * 32];
    __shared__ unsigned short Blds[2 * 64 * 32];
    const int tid = threadIdx.x;
    const int w = tid >> 6, l = tid & 63;
    const int wm = w >> 1, wn = w & 1;
    const int lane15 = l & 15, quad = l >> 4;
    const int n0 = blockIdx.x * 64;    // grid.x = 8
    const int m0 = blockIdx.y * 64;    // grid.y = 64

    const int srow = w * 16 + (l >> 2);
    const int skof = (l & 3) << 3;

    f32x4 acc[2][2];
    #pragma unroll
    for (int i = 0; i < 2; i++)
        #pragma unroll
        for (int j = 0; j < 2; j++) acc[i][j] = (f32x4){0.f, 0.f, 0.f, 0.f};

    for (int k0 = 0; k0 < DM; k0 += 64) {
        __syncthreads();
        gload16(&ctxb[(size_t)(m0 + srow) * DM + k0 + skof],      (char*)Alds + w * 1024);
        gload16(&ctxb[(size_t)(m0 + srow) * DM + k0 + 32 + skof], (char*)Alds + 4096 + w * 1024);
        gload16(&Wob[(size_t)(n0 + srow) * DM + k0 + skof],       (char*)Blds + w * 1024);
        gload16(&Wob[(size_t)(n0 + srow) * DM + k0 + 32 + skof],  (char*)Blds + 4096 + w * 1024);
        __syncthreads();

        #pragma unroll
        for (int s = 0; s < 2; s++) {
            bf16x8 af2[2], bfr[2];
            #pragma unroll
            for (int i = 0; i < 2; i++)
                af2[i] = *(bf16x8*)&Alds[s * 2048 + (wm * 32 + i * 16 + lane15) * 32 + quad * 8];
            #pragma unroll
            for (int j = 0; j < 2; j++)
                bfr[j] = *(bf16x8*)&Blds[s * 2048 + (wn * 32 + j * 16 + lane15) * 32 + quad * 8];
            #pragma unroll
            for (int i = 0; i < 2; i++)
                #pragma unroll
                for (int j = 0; j < 2; j++)
                    acc[i][j] = __builtin_amdgcn_mfma_f32_16x16x32_bf16(af2[i], bfr[j], acc[i][j], 0, 0, 0);
        }
    }

    #pragma unroll
    for (int i = 0; i < 2; i++) {
        #pragma unroll
        for (int rg = 0; rg < 4; rg++) {
            int m = m0 + wm * 32 + i * 16 + quad * 4 + rg;
            #pragma unroll
            for (int j = 0; j < 2; j++) {
                int n = n0 + wn * 32 + j * 16 + lane15;
                out[(size_t)m * DM + n] = acc[i][j][rg] + bo[n];
            }
        }
    }
}

// ---------------------------------------------------------------------------
extern "C" void kernel_launch(void* const* d_in, const int* in_sizes, int n_in,
                              void* d_out, int out_size, void* d_ws, size_t ws_size,
                              hipStream_t stream)
{
    const float* x   = (const float*)d_in[0];
    const float* Wqk = (const float*)d_in[1];
    const float* bqk = (const float*)d_in[2];
    const float* Wv  = (const float*)d_in[3];
    const float* bv  = (const float*)d_in[4];
    const float* Wo  = (const float*)d_in[5];
    const float* bo  = (const float*)d_in[6];
    float* out = (float*)d_out;

    const size_t NTOK = (size_t)B_N * S_N * DM;   // 2,097,152
    float* Asum = (float*)d_ws;                   // NTOK fp32
    float* zsum = Asum + NTOK;                    // 32768 fp32
    unsigned short* xb   = (unsigned short*)(zsum + 32768);
    unsigned short* Wqkb = xb   + NTOK;
    unsigned short* Wvb  = Wqkb + 524288;
    unsigned short* Wob  = Wvb  + 262144;
    unsigned short* qb   = Wob  + 262144;
    unsigned short* kb_  = qb   + NTOK;
    unsigned short* vtb  = kb_  + NTOK;
    unsigned short* Sptb = vtb  + NTOK;
    unsigned short* ctxb = Sptb + NTOK;

    convert_bf16  <<<dim3(3072),   256, 0, stream>>>(x, Wqk, Wv, Wo, xb, Wqkb, Wvb, Wob);
    gemm_qkv_fused<<<dim3(12, 64), 256, 0, stream>>>(xb, Wqkb, Wvb, bqk, bv, qb, kb_, vtb, Asum, zsum);
    scan_states   <<<dim3(260),    256, 0, stream>>>(Asum, zsum, Sptb);
    attn_mfma     <<<dim3(512),    256, 0, stream>>>(qb, kb_, vtb, Sptb, zsum, ctxb);
    gemm_out_mfma <<<dim3(8, 64),  256, 0, stream>>>(ctxb, Wob, bo, out);
}